// Round 7
// baseline (241.825 us; speedup 1.0000x reference)
//
#include <hip/hip_runtime.h>
#include <hip/hip_bf16.h>
#include <hip/hip_fp16.h>

#define B_ 64
#define V_ 64
#define E_ 4032
#define HID_ 128
#define IN_ 32
#define BV_ (B_ * V_)

typedef __attribute__((ext_vector_type(8))) _Float16 f16x8;
typedef __attribute__((ext_vector_type(4))) float f32x4;

// ---------------- Kernel 1: merged prep ----------------
// seg0 [0,2048):      h1 halves (f16), 2 nodes/block
// seg1 [2048,2240):   W2 -> f16 fragment order (edge kernel layout)
// seg2 [2240,2400):   fc1/fc2/mu -> f16 fragment order (out kernel layout)
// seg3 [2400,2528):   x -> f16
// seg4 [2528,6624):   edge-weight gather -> ewT[bv][tt*64+r]
__global__ void __launch_bounds__(256) prep_all(
    const float* __restrict__ x, const float* __restrict__ w1,
    const float* __restrict__ b1, const float* __restrict__ w2,
    const float* __restrict__ edges, const float* __restrict__ fc1w,
    const float* __restrict__ fc2w, const float* __restrict__ muw,
    _Float16* __restrict__ h1r, _Float16* __restrict__ h1s,
    _Float16* __restrict__ w2f, _Float16* __restrict__ fc1f,
    _Float16* __restrict__ fc2f, _Float16* __restrict__ muf,
    _Float16* __restrict__ xh, float* __restrict__ ewT) {
  const int bid = blockIdx.x, t = threadIdx.x;

  if (bid < 2048) {  // ---- h1 halves ----
    __shared__ float xs[2][IN_];
    if (t < 64) xs[t >> 5][t & 31] = x[bid * 64 + t];
    __syncthreads();
    const int h = t & 127, half_ = t >> 7;
#pragma unroll
    for (int tt = 0; tt < 3; ++tt) {
      const float* wrow = w1 + ((size_t)((tt + 1) * HID_ + h)) * (2 * IN_) + half_ * IN_;
      float4 w[8];
#pragma unroll
      for (int j = 0; j < 8; ++j) w[j] = ((const float4*)wrow)[j];
      const float bias = half_ ? 0.f : b1[(tt + 1) * HID_ + h];
      _Float16* dst = (half_ ? h1s : h1r) + ((size_t)tt * BV_ + bid * 2) * HID_ + h;
#pragma unroll
      for (int n = 0; n < 2; ++n) {
        float acc = bias;
#pragma unroll
        for (int j = 0; j < 8; ++j)
          acc += w[j].x * xs[n][4 * j] + w[j].y * xs[n][4 * j + 1] +
                 w[j].z * xs[n][4 * j + 2] + w[j].w * xs[n][4 * j + 3];
        dst[n * HID_] = (_Float16)acc;
      }
    }
    return;
  }
  if (bid < 2240) {  // ---- W2 fragment order: ((((tt*4+w)*2+nt)*4+ks)*64+lane)*8+e
    const int i = (bid - 2048) * 256 + t;
    const int e = i & 7, lane = (i >> 3) & 63, ks = (i >> 9) & 3;
    const int nt = (i >> 11) & 1, w = (i >> 12) & 3, tt = i >> 14;
    const int o = w * 32 + nt * 16 + (lane & 15);
    const int k = ks * 32 + (lane >> 4) * 8 + e;
    w2f[i] = (_Float16)w2[((size_t)((tt + 1) * HID_ + o)) * HID_ + k];
    return;
  }
  if (bid < 2400) {  // ---- out-MLP weights, fragment order ----
    int i = (bid - 2240) * 256 + t;  // < 40960
    if (i < 20480) {  // fc1f: ((ntg*5+ks)*64+lane)*8+e, ntg<8, ks<5, K=160
      const int e = i & 7, lane = (i >> 3) & 63, rest = i >> 9;
      const int ks = rest % 5, ntg = rest / 5;
      const int o = ntg * 16 + (lane & 15);
      const int k = ks * 32 + (lane >> 4) * 8 + e;
      fc1f[i] = (_Float16)fc1w[(size_t)o * (IN_ + HID_) + k];
      return;
    }
    i -= 20480;
    if (i < 16384) {  // fc2f: ((ntg*4+ks)*64+lane)*8+e
      const int e = i & 7, lane = (i >> 3) & 63, rest = i >> 9;
      const int ks = rest & 3, ntg = rest >> 2;
      const int o = ntg * 16 + (lane & 15);
      const int k = ks * 32 + (lane >> 4) * 8 + e;
      fc2f[i] = (_Float16)fc2w[(size_t)o * HID_ + k];
      return;
    }
    i -= 16384;
    {  // muf: ((ntg*4+ks)*64+lane)*8+e, ntg<2
      const int e = i & 7, lane = (i >> 3) & 63, rest = i >> 9;
      const int ks = rest & 3, ntg = rest >> 2;
      const int o = ntg * 16 + (lane & 15);
      const int k = ks * 32 + (lane >> 4) * 8 + e;
      muf[i] = (_Float16)muw[(size_t)o * HID_ + k];
      return;
    }
  }
  if (bid < 2528) {  // ---- x -> f16, 4 elems/thread ----
    const int i4 = ((bid - 2400) * 256 + t) * 4;
    float4 v4 = *(const float4*)(x + i4);
    _Float16 o[4] = {(_Float16)v4.x, (_Float16)v4.y, (_Float16)v4.z, (_Float16)v4.w};
    *(uint2*)(xh + i4) = *(const uint2*)o;
    return;
  }
  {  // ---- edge-weight gather ----
    const int g = bid - 2528;  // b*64+v
    if (t < 192) {
      const int b = g >> 6, v = g & 63;
      const int tt = t >> 6, r = t & 63;
      float val = 0.f;
      if (r < 63) {
        const int u = (r < v) ? r : r + 1;
        const int vv = (v > u) ? v - 1 : v;
        val = edges[((size_t)b * E_ + u * 63 + vv) * 4 + tt + 1];
      }
      ewT[(size_t)g * 192 + t] = val;
    }
    return;
  }
}

// ---------------- Kernel 2: per (b,v) edge MFMA — zero LDS, zero barriers ----------------
// 4 waves, wave nh owns output cols nh*32..+31 (2 n-tiles). A-fragments built
// directly in registers from global h1r/h1s (16B loads, L1-resident slices).
__global__ void __launch_bounds__(256, 4)
edge_mfma(const float* __restrict__ b2, const _Float16* __restrict__ h1r,
          const _Float16* __restrict__ h1s, const _Float16* __restrict__ w2f,
          const float* __restrict__ ewT, _Float16* __restrict__ aggh) {
  const int v = blockIdx.x, b = blockIdx.y, t = threadIdx.x;
  const int nh = t >> 6, lane = t & 63;
  const int l15 = lane & 15, lg = lane >> 4;
  const int bv = b * V_ + v;

  float acc[4][2][4];
#pragma unroll
  for (int mt = 0; mt < 4; ++mt)
#pragma unroll
    for (int nt = 0; nt < 2; ++nt)
#pragma unroll
      for (int r = 0; r < 4; ++r) acc[mt][nt][r] = 0.f;

#pragma unroll
  for (int tt = 0; tt < 3; ++tt) {
    const _Float16* hrp = h1r + ((size_t)(tt * B_ + b) * V_ + v) * HID_;
    f16x8 hr[4];
#pragma unroll
    for (int ks = 0; ks < 4; ++ks) hr[ks] = *(const f16x8*)(hrp + ks * 32 + lg * 8);

    f16x8 bf[2][4];
    float b2r[2];
#pragma unroll
    for (int nt = 0; nt < 2; ++nt) {
#pragma unroll
      for (int ks = 0; ks < 4; ++ks)
        bf[nt][ks] = *(const f16x8*)(
            w2f + (size_t)(((((tt * 4 + nh) * 2 + nt) * 4 + ks) * 64 + lane)) * 8);
      b2r[nt] = b2[(tt + 1) * HID_ + nh * 32 + nt * 16 + l15];
    }

    const _Float16* hsb = h1s + ((size_t)(tt * B_ + b) * V_) * HID_;
#pragma unroll
    for (int mt = 0; mt < 4; ++mt) {
      const int r = mt * 16 + l15;
      int u = (r < v) ? r : r + 1;
      if (r == 63) u = v;  // dummy row, ew=0
      f16x8 af[4];
#pragma unroll
      for (int ks = 0; ks < 4; ++ks) {
        f16x8 hs = *(const f16x8*)(hsb + (size_t)u * HID_ + ks * 32 + lg * 8);
        af[ks] = __builtin_elementwise_max(hr[ks] + hs, (f16x8)0);
      }
      const float4 ew4 = *(const float4*)(ewT + (size_t)bv * 192 + tt * 64 + mt * 16 + lg * 4);
#pragma unroll
      for (int nt = 0; nt < 2; ++nt) {
        f32x4 macc = {0.f, 0.f, 0.f, 0.f};
#pragma unroll
        for (int ks = 0; ks < 4; ++ks)
          macc = __builtin_amdgcn_mfma_f32_16x16x32_f16(af[ks], bf[nt][ks], macc, 0, 0, 0);
        acc[mt][nt][0] += fmaxf(macc[0] + b2r[nt], 0.f) * ew4.x;
        acc[mt][nt][1] += fmaxf(macc[1] + b2r[nt], 0.f) * ew4.y;
        acc[mt][nt][2] += fmaxf(macc[2] + b2r[nt], 0.f) * ew4.z;
        acc[mt][nt][3] += fmaxf(macc[3] + b2r[nt], 0.f) * ew4.w;
      }
    }
  }

  // reduce 64 edge rows -> agg (f16)
#pragma unroll
  for (int nt = 0; nt < 2; ++nt) {
    float s = 0.f;
#pragma unroll
    for (int mt = 0; mt < 4; ++mt)
#pragma unroll
      for (int r = 0; r < 4; ++r) s += acc[mt][nt][r];
    s += __shfl_xor(s, 16);
    s += __shfl_xor(s, 32);
    if (lane < 16) aggh[(size_t)bv * HID_ + nh * 32 + nt * 16 + l15] = (_Float16)s;
  }
}

// ---------------- Kernel 3: output MLP via MFMA, 32 nodes/block ----------------
// wave = (mh = rows half, nh = cols half). aug = [xh | aggh] read as 16B frags.
__global__ void __launch_bounds__(256)
out_mlp(const float* __restrict__ x, const _Float16* __restrict__ xh,
        const _Float16* __restrict__ aggh, const _Float16* __restrict__ fc1f,
        const float* __restrict__ fc1b, const _Float16* __restrict__ fc2f,
        const float* __restrict__ fc2b, const _Float16* __restrict__ muf,
        const float* __restrict__ mub, float* __restrict__ out) {
  const int t = threadIdx.x;
  const int lane = t & 63, l15 = lane & 15, lg = lane >> 4;
  const int mh = (t >> 6) & 1, nh = t >> 7;
  const int nb = blockIdx.x * 32;

  __shared__ __align__(16) _Float16 p1h[32][136];
  __shared__ __align__(16) _Float16 p2h[32][136];

  // ---- fc1: rows mh*16+l15, cols nh*64 (4 nt), K=160 (5 ks) ----
  const int arow = nb + mh * 16 + l15;
  float4 acc1[4] = {{0, 0, 0, 0}, {0, 0, 0, 0}, {0, 0, 0, 0}, {0, 0, 0, 0}};
#pragma unroll
  for (int ks = 0; ks < 5; ++ks) {
    f16x8 af = (ks == 0)
                   ? *(const f16x8*)(xh + (size_t)arow * IN_ + lg * 8)
                   : *(const f16x8*)(aggh + (size_t)arow * HID_ + (ks - 1) * 32 + lg * 8);
#pragma unroll
    for (int nt = 0; nt < 4; ++nt) {
      f16x8 bf = *(const f16x8*)(fc1f + (size_t)((((nh * 4 + nt) * 5 + ks) * 64 + lane)) * 8);
      *(f32x4*)&acc1[nt] =
          __builtin_amdgcn_mfma_f32_16x16x32_f16(af, bf, *(f32x4*)&acc1[nt], 0, 0, 0);
    }
  }
#pragma unroll
  for (int nt = 0; nt < 4; ++nt) {
    const int col = nh * 64 + nt * 16 + l15;
    const float bias = fc1b[col];
    p1h[mh * 16 + lg * 4 + 0][col] = (_Float16)fmaxf(acc1[nt].x + bias, 0.f);
    p1h[mh * 16 + lg * 4 + 1][col] = (_Float16)fmaxf(acc1[nt].y + bias, 0.f);
    p1h[mh * 16 + lg * 4 + 2][col] = (_Float16)fmaxf(acc1[nt].z + bias, 0.f);
    p1h[mh * 16 + lg * 4 + 3][col] = (_Float16)fmaxf(acc1[nt].w + bias, 0.f);
  }
  __syncthreads();

  // ---- fc2: K=128 (4 ks) ----
  float4 acc2[4] = {{0, 0, 0, 0}, {0, 0, 0, 0}, {0, 0, 0, 0}, {0, 0, 0, 0}};
#pragma unroll
  for (int ks = 0; ks < 4; ++ks) {
    f16x8 af = *(const f16x8*)&p1h[mh * 16 + l15][ks * 32 + lg * 8];
#pragma unroll
    for (int nt = 0; nt < 4; ++nt) {
      f16x8 bf = *(const f16x8*)(fc2f + (size_t)((((nh * 4 + nt) * 4 + ks) * 64 + lane)) * 8);
      *(f32x4*)&acc2[nt] =
          __builtin_amdgcn_mfma_f32_16x16x32_f16(af, bf, *(f32x4*)&acc2[nt], 0, 0, 0);
    }
  }
#pragma unroll
  for (int nt = 0; nt < 4; ++nt) {
    const int col = nh * 64 + nt * 16 + l15;
    const float bias = fc2b[col];
    p2h[mh * 16 + lg * 4 + 0][col] = (_Float16)fmaxf(acc2[nt].x + bias, 0.f);
    p2h[mh * 16 + lg * 4 + 1][col] = (_Float16)fmaxf(acc2[nt].y + bias, 0.f);
    p2h[mh * 16 + lg * 4 + 2][col] = (_Float16)fmaxf(acc2[nt].z + bias, 0.f);
    p2h[mh * 16 + lg * 4 + 3][col] = (_Float16)fmaxf(acc2[nt].w + bias, 0.f);
  }
  __syncthreads();

  // ---- mu: N=32 split by nh (cols nh*16), K=128 ----
  float4 acc3 = {0, 0, 0, 0};
#pragma unroll
  for (int ks = 0; ks < 4; ++ks) {
    f16x8 af = *(const f16x8*)&p2h[mh * 16 + l15][ks * 32 + lg * 8];
    f16x8 bf = *(const f16x8*)(muf + (size_t)(((nh * 4 + ks) * 64 + lane)) * 8);
    *(f32x4*)&acc3 = __builtin_amdgcn_mfma_f32_16x16x32_f16(af, bf, *(f32x4*)&acc3, 0, 0, 0);
  }
  const int col = nh * 16 + l15;
  const float mb = mub[col];
#pragma unroll
  for (int r = 0; r < 4; ++r) {
    const int node = nb + mh * 16 + lg * 4 + r;
    out[(size_t)node * IN_ + col] =
        x[(size_t)node * IN_ + col] + ((const float*)&acc3)[r] + mb;
  }
}

extern "C" void kernel_launch(void* const* d_in, const int* in_sizes, int n_in,
                              void* d_out, int out_size, void* d_ws, size_t ws_size,
                              hipStream_t stream) {
  const float* x     = (const float*)d_in[0];
  const float* edges = (const float*)d_in[1];
  const float* w1    = (const float*)d_in[2];
  const float* b1    = (const float*)d_in[3];
  const float* w2    = (const float*)d_in[4];
  const float* b2    = (const float*)d_in[5];
  const float* fc1w  = (const float*)d_in[6];
  const float* fc1b  = (const float*)d_in[7];
  const float* fc2w  = (const float*)d_in[8];
  const float* fc2b  = (const float*)d_in[9];
  const float* muw   = (const float*)d_in[10];
  const float* mub   = (const float*)d_in[11];
  float* out = (float*)d_out;

  float* ewT    = (float*)d_ws;                         // 4096*192 f32
  _Float16* h1r = (_Float16*)(ewT + (size_t)BV_ * 192); // 3*4096*128
  _Float16* h1s = h1r + (size_t)3 * BV_ * HID_;         // 3*4096*128
  _Float16* w2f = h1s + (size_t)3 * BV_ * HID_;         // 49152
  _Float16* fc1f = w2f + 49152;                         // 20480
  _Float16* fc2f = fc1f + 20480;                        // 16384
  _Float16* muf  = fc2f + 16384;                        // 4096
  _Float16* xh   = muf + 4096;                          // 4096*32
  _Float16* aggh = xh + (size_t)BV_ * IN_;              // 4096*128

  prep_all<<<6624, 256, 0, stream>>>(x, w1, b1, w2, edges, fc1w, fc2w, muw,
                                     h1r, h1s, w2f, fc1f, fc2f, muf, xh, ewT);
  edge_mfma<<<dim3(V_, B_), 256, 0, stream>>>(b2, h1r, h1s, w2f, ewT, aggh);
  out_mlp<<<BV_ / 32, 256, 0, stream>>>(x, xh, aggh, fc1f, fc1b, fc2f, fc2b,
                                        muf, mub, out);
}

// Round 10
// 215.566 us; speedup vs baseline: 1.1218x; 1.1218x over previous
//
#include <hip/hip_runtime.h>
#include <hip/hip_bf16.h>
#include <hip/hip_fp16.h>

#define B_ 64
#define V_ 64
#define E_ 4032
#define HID_ 128
#define IN_ 32
#define BV_ (B_ * V_)

typedef __attribute__((ext_vector_type(8))) _Float16 f16x8;
typedef __attribute__((ext_vector_type(4))) float f32x4;

// ---------------- Kernel 1: merged prep ----------------
// seg0 [0,256):     h1 halves (f16), 16 nodes/block, W1 rows reg-cached
// seg1 [256,448):   W2 -> f16 fragment order (edge kernel layout)
// seg2 [448,608):   fc1/fc2/mu -> f16 fragment order (out kernel layout)
// seg3 [608,736):   x -> f16
// seg4 [736,4832):  edge-weight gather -> ewT[bv][tt*64+r]
__global__ void __launch_bounds__(256) prep_all(
    const float* __restrict__ x, const float* __restrict__ w1,
    const float* __restrict__ b1, const float* __restrict__ w2,
    const float* __restrict__ edges, const float* __restrict__ fc1w,
    const float* __restrict__ fc2w, const float* __restrict__ muw,
    _Float16* __restrict__ h1r, _Float16* __restrict__ h1s,
    _Float16* __restrict__ w2f, _Float16* __restrict__ fc1f,
    _Float16* __restrict__ fc2f, _Float16* __restrict__ muf,
    _Float16* __restrict__ xh, float* __restrict__ ewT) {
  const int bid = blockIdx.x, t = threadIdx.x;

  if (bid < 256) {  // ---- h1 halves, 16 nodes/block ----
    __shared__ float xs[16][IN_];
    for (int i = t; i < 16 * IN_; i += 256) xs[i >> 5][i & 31] = x[bid * 16 * IN_ + i];
    __syncthreads();
    const int h = t & 127, half_ = t >> 7;
#pragma unroll
    for (int tt = 0; tt < 3; ++tt) {
      const float* wrow = w1 + ((size_t)((tt + 1) * HID_ + h)) * (2 * IN_) + half_ * IN_;
      float4 w[8];
#pragma unroll
      for (int j = 0; j < 8; ++j) w[j] = ((const float4*)wrow)[j];
      const float bias = half_ ? 0.f : b1[(tt + 1) * HID_ + h];
      _Float16* dst = (half_ ? h1s : h1r) + ((size_t)tt * BV_ + bid * 16) * HID_ + h;
#pragma unroll
      for (int n = 0; n < 16; ++n) {
        float acc = bias;
#pragma unroll
        for (int j = 0; j < 8; ++j)
          acc += w[j].x * xs[n][4 * j] + w[j].y * xs[n][4 * j + 1] +
                 w[j].z * xs[n][4 * j + 2] + w[j].w * xs[n][4 * j + 3];
        dst[n * HID_] = (_Float16)acc;  // 64-lane contiguous f16 store
      }
    }
    return;
  }
  if (bid < 448) {  // ---- W2 fragment order: ((((tt*4+w)*2+nt)*4+ks)*64+lane)*8+e
    const int i = (bid - 256) * 256 + t;
    const int e = i & 7, lane = (i >> 3) & 63, ks = (i >> 9) & 3;
    const int nt = (i >> 11) & 1, w = (i >> 12) & 3, tt = i >> 14;
    const int o = w * 32 + nt * 16 + (lane & 15);
    const int k = ks * 32 + (lane >> 4) * 8 + e;
    w2f[i] = (_Float16)w2[((size_t)((tt + 1) * HID_ + o)) * HID_ + k];
    return;
  }
  if (bid < 608) {  // ---- out-MLP weights, fragment order ----
    int i = (bid - 448) * 256 + t;  // < 40960
    if (i < 20480) {  // fc1f: ((ntg*5+ks)*64+lane)*8+e, ntg<8, ks<5, K=160
      const int e = i & 7, lane = (i >> 3) & 63, rest = i >> 9;
      const int ks = rest % 5, ntg = rest / 5;
      const int o = ntg * 16 + (lane & 15);
      const int k = ks * 32 + (lane >> 4) * 8 + e;
      fc1f[i] = (_Float16)fc1w[(size_t)o * (IN_ + HID_) + k];
      return;
    }
    i -= 20480;
    if (i < 16384) {  // fc2f: ((ntg*4+ks)*64+lane)*8+e
      const int e = i & 7, lane = (i >> 3) & 63, rest = i >> 9;
      const int ks = rest & 3, ntg = rest >> 2;
      const int o = ntg * 16 + (lane & 15);
      const int k = ks * 32 + (lane >> 4) * 8 + e;
      fc2f[i] = (_Float16)fc2w[(size_t)o * HID_ + k];
      return;
    }
    i -= 16384;
    {  // muf: ((ntg*4+ks)*64+lane)*8+e, ntg<2
      const int e = i & 7, lane = (i >> 3) & 63, rest = i >> 9;
      const int ks = rest & 3, ntg = rest >> 2;
      const int o = ntg * 16 + (lane & 15);
      const int k = ks * 32 + (lane >> 4) * 8 + e;
      muf[i] = (_Float16)muw[(size_t)o * HID_ + k];
      return;
    }
  }
  if (bid < 736) {  // ---- x -> f16, 4 elems/thread ----
    const int i4 = ((bid - 608) * 256 + t) * 4;
    float4 v4 = *(const float4*)(x + i4);
    _Float16 o[4] = {(_Float16)v4.x, (_Float16)v4.y, (_Float16)v4.z, (_Float16)v4.w};
    *(uint2*)(xh + i4) = *(const uint2*)o;
    return;
  }
  {  // ---- edge-weight gather ----
    const int g = bid - 736;  // b*64+v
    if (t < 192) {
      const int b = g >> 6, v = g & 63;
      const int tt = t >> 6, r = t & 63;
      float val = 0.f;
      if (r < 63) {
        const int u = (r < v) ? r : r + 1;
        const int vv = (v > u) ? v - 1 : v;
        val = edges[((size_t)b * E_ + u * 63 + vv) * 4 + tt + 1];
      }
      ewT[(size_t)g * 192 + t] = val;
    }
    return;
  }
}

// ---------------- Kernel 2: per (b,v) edge MFMA — zero LDS, zero barriers ----------------
// NO min-waves bound (R5's ",4" forced VGPR=64 -> scratch spills, 113MB writes).
// XCD swizzle: 512 contiguous (b,v) per XCD -> h1/w2f slices L2-resident per XCD.
__global__ void __launch_bounds__(256)
edge_mfma(const float* __restrict__ b2, const _Float16* __restrict__ h1r,
          const _Float16* __restrict__ h1s, const _Float16* __restrict__ w2f,
          const float* __restrict__ ewT, _Float16* __restrict__ aggh) {
  const int bid = blockIdx.x;
  const int nb = (bid & 7) * 512 + (bid >> 3);  // bijective: 4096 % 8 == 0
  const int b = nb >> 6, v = nb & 63;
  const int t = threadIdx.x;
  const int nh = t >> 6, lane = t & 63;
  const int l15 = lane & 15, lg = lane >> 4;
  const int bv = nb;

  float acc[4][2][4];
#pragma unroll
  for (int mt = 0; mt < 4; ++mt)
#pragma unroll
    for (int nt = 0; nt < 2; ++nt)
#pragma unroll
      for (int r = 0; r < 4; ++r) acc[mt][nt][r] = 0.f;

#pragma unroll
  for (int tt = 0; tt < 3; ++tt) {
    const _Float16* hrp = h1r + ((size_t)(tt * B_ + b) * V_ + v) * HID_;
    f16x8 hr[4];
#pragma unroll
    for (int ks = 0; ks < 4; ++ks) hr[ks] = *(const f16x8*)(hrp + ks * 32 + lg * 8);

    f16x8 bf[2][4];
    float b2r[2];
#pragma unroll
    for (int nt = 0; nt < 2; ++nt) {
#pragma unroll
      for (int ks = 0; ks < 4; ++ks)
        bf[nt][ks] = *(const f16x8*)(
            w2f + (size_t)(((((tt * 4 + nh) * 2 + nt) * 4 + ks) * 64 + lane)) * 8);
      b2r[nt] = b2[(tt + 1) * HID_ + nh * 32 + nt * 16 + l15];
    }

    const _Float16* hsb = h1s + ((size_t)(tt * B_ + b) * V_) * HID_;
#pragma unroll
    for (int mt = 0; mt < 4; ++mt) {
      const int r = mt * 16 + l15;
      int u = (r < v) ? r : r + 1;
      if (r == 63) u = v;  // dummy row, ew=0
      f16x8 af[4];
#pragma unroll
      for (int ks = 0; ks < 4; ++ks) {
        f16x8 hs = *(const f16x8*)(hsb + (size_t)u * HID_ + ks * 32 + lg * 8);
        af[ks] = __builtin_elementwise_max(hr[ks] + hs, (f16x8)0);
      }
      const float4 ew4 = *(const float4*)(ewT + (size_t)bv * 192 + tt * 64 + mt * 16 + lg * 4);
#pragma unroll
      for (int nt = 0; nt < 2; ++nt) {
        f32x4 macc = {0.f, 0.f, 0.f, 0.f};
#pragma unroll
        for (int ks = 0; ks < 4; ++ks)
          macc = __builtin_amdgcn_mfma_f32_16x16x32_f16(af[ks], bf[nt][ks], macc, 0, 0, 0);
        acc[mt][nt][0] += fmaxf(macc[0] + b2r[nt], 0.f) * ew4.x;
        acc[mt][nt][1] += fmaxf(macc[1] + b2r[nt], 0.f) * ew4.y;
        acc[mt][nt][2] += fmaxf(macc[2] + b2r[nt], 0.f) * ew4.z;
        acc[mt][nt][3] += fmaxf(macc[3] + b2r[nt], 0.f) * ew4.w;
      }
    }
  }

  // reduce 64 edge rows -> agg (f16). After the xor-reduce, s depends only on
  // l15, so lanes 16..31 hold valid nt=1 values -> one 64B contiguous store.
  float sv[2];
#pragma unroll
  for (int nt = 0; nt < 2; ++nt) {
    float s = 0.f;
#pragma unroll
    for (int mt = 0; mt < 4; ++mt)
#pragma unroll
      for (int r = 0; r < 4; ++r) s += acc[mt][nt][r];
    s += __shfl_xor(s, 16);
    s += __shfl_xor(s, 32);
    sv[nt] = s;
  }
  if (lane < 32)
    aggh[(size_t)bv * HID_ + nh * 32 + lane] = (_Float16)((lane < 16) ? sv[0] : sv[1]);
}

// ---------------- Kernel 3: output MLP via MFMA, 32 nodes/block ----------------
__global__ void __launch_bounds__(256)
out_mlp(const float* __restrict__ x, const _Float16* __restrict__ xh,
        const _Float16* __restrict__ aggh, const _Float16* __restrict__ fc1f,
        const float* __restrict__ fc1b, const _Float16* __restrict__ fc2f,
        const float* __restrict__ fc2b, const _Float16* __restrict__ muf,
        const float* __restrict__ mub, float* __restrict__ out) {
  const int t = threadIdx.x;
  const int lane = t & 63, l15 = lane & 15, lg = lane >> 4;
  const int mh = (t >> 6) & 1, nh = t >> 7;
  const int nb = blockIdx.x * 32;

  __shared__ __align__(16) _Float16 p1h[32][136];
  __shared__ __align__(16) _Float16 p2h[32][136];

  // ---- fc1: rows mh*16+l15, cols nh*64 (4 nt), K=160 (5 ks) ----
  const int arow = nb + mh * 16 + l15;
  float4 acc1[4] = {{0, 0, 0, 0}, {0, 0, 0, 0}, {0, 0, 0, 0}, {0, 0, 0, 0}};
#pragma unroll
  for (int ks = 0; ks < 5; ++ks) {
    f16x8 af = (ks == 0)
                   ? *(const f16x8*)(xh + (size_t)arow * IN_ + lg * 8)
                   : *(const f16x8*)(aggh + (size_t)arow * HID_ + (ks - 1) * 32 + lg * 8);
#pragma unroll
    for (int nt = 0; nt < 4; ++nt) {
      f16x8 bf = *(const f16x8*)(fc1f + (size_t)((((nh * 4 + nt) * 5 + ks) * 64 + lane)) * 8);
      *(f32x4*)&acc1[nt] =
          __builtin_amdgcn_mfma_f32_16x16x32_f16(af, bf, *(f32x4*)&acc1[nt], 0, 0, 0);
    }
  }
#pragma unroll
  for (int nt = 0; nt < 4; ++nt) {
    const int col = nh * 64 + nt * 16 + l15;
    const float bias = fc1b[col];
    p1h[mh * 16 + lg * 4 + 0][col] = (_Float16)fmaxf(acc1[nt].x + bias, 0.f);
    p1h[mh * 16 + lg * 4 + 1][col] = (_Float16)fmaxf(acc1[nt].y + bias, 0.f);
    p1h[mh * 16 + lg * 4 + 2][col] = (_Float16)fmaxf(acc1[nt].z + bias, 0.f);
    p1h[mh * 16 + lg * 4 + 3][col] = (_Float16)fmaxf(acc1[nt].w + bias, 0.f);
  }
  __syncthreads();

  // ---- fc2: K=128 (4 ks) ----
  float4 acc2[4] = {{0, 0, 0, 0}, {0, 0, 0, 0}, {0, 0, 0, 0}, {0, 0, 0, 0}};
#pragma unroll
  for (int ks = 0; ks < 4; ++ks) {
    f16x8 af = *(const f16x8*)&p1h[mh * 16 + l15][ks * 32 + lg * 8];
#pragma unroll
    for (int nt = 0; nt < 4; ++nt) {
      f16x8 bf = *(const f16x8*)(fc2f + (size_t)((((nh * 4 + nt) * 4 + ks) * 64 + lane)) * 8);
      *(f32x4*)&acc2[nt] =
          __builtin_amdgcn_mfma_f32_16x16x32_f16(af, bf, *(f32x4*)&acc2[nt], 0, 0, 0);
    }
  }
#pragma unroll
  for (int nt = 0; nt < 4; ++nt) {
    const int col = nh * 64 + nt * 16 + l15;
    const float bias = fc2b[col];
    p2h[mh * 16 + lg * 4 + 0][col] = (_Float16)fmaxf(acc2[nt].x + bias, 0.f);
    p2h[mh * 16 + lg * 4 + 1][col] = (_Float16)fmaxf(acc2[nt].y + bias, 0.f);
    p2h[mh * 16 + lg * 4 + 2][col] = (_Float16)fmaxf(acc2[nt].z + bias, 0.f);
    p2h[mh * 16 + lg * 4 + 3][col] = (_Float16)fmaxf(acc2[nt].w + bias, 0.f);
  }
  __syncthreads();

  // ---- mu: N=32 split by nh (cols nh*16), K=128 ----
  float4 acc3 = {0, 0, 0, 0};
#pragma unroll
  for (int ks = 0; ks < 4; ++ks) {
    f16x8 af = *(const f16x8*)&p2h[mh * 16 + l15][ks * 32 + lg * 8];
    f16x8 bf = *(const f16x8*)(muf + (size_t)(((nh * 4 + ks) * 64 + lane)) * 8);
    *(f32x4*)&acc3 = __builtin_amdgcn_mfma_f32_16x16x32_f16(af, bf, *(f32x4*)&acc3, 0, 0, 0);
  }
  const int col = nh * 16 + l15;
  const float mb = mub[col];
#pragma unroll
  for (int r = 0; r < 4; ++r) {
    const int node = nb + mh * 16 + lg * 4 + r;
    out[(size_t)node * IN_ + col] =
        x[(size_t)node * IN_ + col] + ((const float*)&acc3)[r] + mb;
  }
}

extern "C" void kernel_launch(void* const* d_in, const int* in_sizes, int n_in,
                              void* d_out, int out_size, void* d_ws, size_t ws_size,
                              hipStream_t stream) {
  const float* x     = (const float*)d_in[0];
  const float* edges = (const float*)d_in[1];
  const float* w1    = (const float*)d_in[2];
  const float* b1    = (const float*)d_in[3];
  const float* w2    = (const float*)d_in[4];
  const float* b2    = (const float*)d_in[5];
  const float* fc1w  = (const float*)d_in[6];
  const float* fc1b  = (const float*)d_in[7];
  const float* fc2w  = (const float*)d_in[8];
  const float* fc2b  = (const float*)d_in[9];
  const float* muw   = (const float*)d_in[10];
  const float* mub   = (const float*)d_in[11];
  float* out = (float*)d_out;

  float* ewT    = (float*)d_ws;                         // 4096*192 f32
  _Float16* h1r = (_Float16*)(ewT + (size_t)BV_ * 192); // 3*4096*128
  _Float16* h1s = h1r + (size_t)3 * BV_ * HID_;         // 3*4096*128
  _Float16* w2f = h1s + (size_t)3 * BV_ * HID_;         // 49152
  _Float16* fc1f = w2f + 49152;                         // 20480
  _Float16* fc2f = fc1f + 20480;                        // 16384
  _Float16* muf  = fc2f + 16384;                        // 4096
  _Float16* xh   = muf + 4096;                          // 4096*32
  _Float16* aggh = xh + (size_t)BV_ * IN_;              // 4096*128

  prep_all<<<4832, 256, 0, stream>>>(x, w1, b1, w2, edges, fc1w, fc2w, muw,
                                     h1r, h1s, w2f, fc1f, fc2f, muf, xh, ewT);
  edge_mfma<<<BV_, 256, 0, stream>>>(b2, h1r, h1s, w2f, ewT, aggh);
  out_mlp<<<BV_ / 32, 256, 0, stream>>>(x, xh, aggh, fc1f, fc1b, fc2f, fc2b,
                                        muf, mub, out);
}

// Round 11
// 160.214 us; speedup vs baseline: 1.5094x; 1.3455x over previous
//
#include <hip/hip_runtime.h>
#include <hip/hip_bf16.h>
#include <hip/hip_fp16.h>

#define B_ 64
#define V_ 64
#define E_ 4032
#define HID_ 128
#define IN_ 32
#define BV_ (B_ * V_)

typedef __attribute__((ext_vector_type(8))) _Float16 f16x8;
typedef __attribute__((ext_vector_type(4))) float f32x4;

// ---------------- Kernel 1: merged prep (unchanged from R7) ----------------
__global__ void __launch_bounds__(256) prep_all(
    const float* __restrict__ x, const float* __restrict__ w1,
    const float* __restrict__ b1, const float* __restrict__ w2,
    const float* __restrict__ edges, const float* __restrict__ fc1w,
    const float* __restrict__ fc2w, const float* __restrict__ muw,
    _Float16* __restrict__ h1r, _Float16* __restrict__ h1s,
    _Float16* __restrict__ w2f, _Float16* __restrict__ fc1f,
    _Float16* __restrict__ fc2f, _Float16* __restrict__ muf,
    _Float16* __restrict__ xh, float* __restrict__ ewT) {
  const int bid = blockIdx.x, t = threadIdx.x;

  if (bid < 256) {  // ---- h1 halves, 16 nodes/block ----
    __shared__ float xs[16][IN_];
    for (int i = t; i < 16 * IN_; i += 256) xs[i >> 5][i & 31] = x[bid * 16 * IN_ + i];
    __syncthreads();
    const int h = t & 127, half_ = t >> 7;
#pragma unroll
    for (int tt = 0; tt < 3; ++tt) {
      const float* wrow = w1 + ((size_t)((tt + 1) * HID_ + h)) * (2 * IN_) + half_ * IN_;
      float4 w[8];
#pragma unroll
      for (int j = 0; j < 8; ++j) w[j] = ((const float4*)wrow)[j];
      const float bias = half_ ? 0.f : b1[(tt + 1) * HID_ + h];
      _Float16* dst = (half_ ? h1s : h1r) + ((size_t)tt * BV_ + bid * 16) * HID_ + h;
#pragma unroll
      for (int n = 0; n < 16; ++n) {
        float acc = bias;
#pragma unroll
        for (int j = 0; j < 8; ++j)
          acc += w[j].x * xs[n][4 * j] + w[j].y * xs[n][4 * j + 1] +
                 w[j].z * xs[n][4 * j + 2] + w[j].w * xs[n][4 * j + 3];
        dst[n * HID_] = (_Float16)acc;
      }
    }
    return;
  }
  if (bid < 448) {  // ---- W2 fragment order ----
    const int i = (bid - 256) * 256 + t;
    const int e = i & 7, lane = (i >> 3) & 63, ks = (i >> 9) & 3;
    const int nt = (i >> 11) & 1, w = (i >> 12) & 3, tt = i >> 14;
    const int o = w * 32 + nt * 16 + (lane & 15);
    const int k = ks * 32 + (lane >> 4) * 8 + e;
    w2f[i] = (_Float16)w2[((size_t)((tt + 1) * HID_ + o)) * HID_ + k];
    return;
  }
  if (bid < 608) {  // ---- out-MLP weights, fragment order ----
    int i = (bid - 448) * 256 + t;
    if (i < 20480) {  // fc1f: ((ntg*5+ks)*64+lane)*8+e
      const int e = i & 7, lane = (i >> 3) & 63, rest = i >> 9;
      const int ks = rest % 5, ntg = rest / 5;
      const int o = ntg * 16 + (lane & 15);
      const int k = ks * 32 + (lane >> 4) * 8 + e;
      fc1f[i] = (_Float16)fc1w[(size_t)o * (IN_ + HID_) + k];
      return;
    }
    i -= 20480;
    if (i < 16384) {  // fc2f
      const int e = i & 7, lane = (i >> 3) & 63, rest = i >> 9;
      const int ks = rest & 3, ntg = rest >> 2;
      const int o = ntg * 16 + (lane & 15);
      const int k = ks * 32 + (lane >> 4) * 8 + e;
      fc2f[i] = (_Float16)fc2w[(size_t)o * HID_ + k];
      return;
    }
    i -= 16384;
    {  // muf
      const int e = i & 7, lane = (i >> 3) & 63, rest = i >> 9;
      const int ks = rest & 3, ntg = rest >> 2;
      const int o = ntg * 16 + (lane & 15);
      const int k = ks * 32 + (lane >> 4) * 8 + e;
      muf[i] = (_Float16)muw[(size_t)o * HID_ + k];
      return;
    }
  }
  if (bid < 736) {  // ---- x -> f16 ----
    const int i4 = ((bid - 608) * 256 + t) * 4;
    float4 v4 = *(const float4*)(x + i4);
    _Float16 o[4] = {(_Float16)v4.x, (_Float16)v4.y, (_Float16)v4.z, (_Float16)v4.w};
    *(uint2*)(xh + i4) = *(const uint2*)o;
    return;
  }
  {  // ---- edge-weight gather ----
    const int g = bid - 736;
    if (t < 192) {
      const int b = g >> 6, v = g & 63;
      const int tt = t >> 6, r = t & 63;
      float val = 0.f;
      if (r < 63) {
        const int u = (r < v) ? r : r + 1;
        const int vv = (v > u) ? v - 1 : v;
        val = edges[((size_t)b * E_ + u * 63 + vv) * 4 + tt + 1];
      }
      ewT[(size_t)g * 192 + t] = val;
    }
    return;
  }
}

// ---------------- Kernel 2: per (b,v) edge MFMA, LDS-staged h1s ----------------
// h1s slice (64 rows x 256B = 16KB) staged coalesced into LDS per type with XOR
// swizzle byte^=(row&7)<<4; af gathers become ds_read_b128 (uniform bank load).
// b2 folded into MFMA C-init. XCD swizzle for L2 residency.
__global__ void __launch_bounds__(256)
edge_mfma(const float* __restrict__ b2, const _Float16* __restrict__ h1r,
          const _Float16* __restrict__ h1s, const _Float16* __restrict__ w2f,
          const float* __restrict__ ewT, _Float16* __restrict__ aggh) {
  const int bid = blockIdx.x;
  const int nb = (bid & 7) * 512 + (bid >> 3);  // bijective: 4096 % 8 == 0
  const int b = nb >> 6, v = nb & 63;
  const int t = threadIdx.x;
  const int nh = t >> 6, lane = t & 63;
  const int l15 = lane & 15, lg = lane >> 4;

  __shared__ __align__(16) _Float16 hsl[64 * HID_];  // 16KB, swizzled rows

  float acc[4][2][4];
#pragma unroll
  for (int mt = 0; mt < 4; ++mt)
#pragma unroll
    for (int nt = 0; nt < 2; ++nt)
#pragma unroll
      for (int r = 0; r < 4; ++r) acc[mt][nt][r] = 0.f;

  // per-lane LDS read offsets for the dummy-safe sender row
  int urow[4];
#pragma unroll
  for (int mt = 0; mt < 4; ++mt) {
    const int r = mt * 16 + l15;
    int u = (r < v) ? r : r + 1;
    if (r == 63) u = v;  // dummy row, ew=0
    urow[mt] = u;
  }

#pragma unroll
  for (int tt = 0; tt < 3; ++tt) {
    // ---- stage h1s[tt][b][*] -> LDS (coalesced, swizzled) ----
    const char* hsb = (const char*)(h1s + ((size_t)(tt * B_ + b) * V_) * HID_);
#pragma unroll
    for (int q = 0; q < 4; ++q) {
      const int byteoff = q * 4096 + t * 16;
      const int row = (byteoff >> 8) & 7;
      f16x8 val = *(const f16x8*)(hsb + byteoff);
      *(f16x8*)((char*)hsl + (byteoff ^ (row << 4))) = val;
    }

    // hr (row v, broadcast lines) + B fragments + bias while staging lands
    const _Float16* hrp = h1r + ((size_t)(tt * B_ + b) * V_ + v) * HID_;
    f16x8 hr[4];
#pragma unroll
    for (int ks = 0; ks < 4; ++ks) hr[ks] = *(const f16x8*)(hrp + ks * 32 + lg * 8);

    f16x8 bf[2][4];
    float b2r[2];
#pragma unroll
    for (int nt = 0; nt < 2; ++nt) {
#pragma unroll
      for (int ks = 0; ks < 4; ++ks)
        bf[nt][ks] = *(const f16x8*)(
            w2f + (size_t)(((((tt * 4 + nh) * 2 + nt) * 4 + ks) * 64 + lane)) * 8);
      b2r[nt] = b2[(tt + 1) * HID_ + nh * 32 + nt * 16 + l15];
    }
    __syncthreads();

#pragma unroll
    for (int mt = 0; mt < 4; ++mt) {
      const int u = urow[mt];
      const char* ubase = (const char*)hsl + u * 256;
      const int sw = (u & 7) << 4;
      f16x8 af[4];
#pragma unroll
      for (int ks = 0; ks < 4; ++ks) {
        f16x8 hs = *(const f16x8*)(ubase + ((ks * 64 + lg * 16) ^ sw));
        af[ks] = __builtin_elementwise_max(hr[ks] + hs, (f16x8)0);
      }
      const float4 ew4 =
          *(const float4*)(ewT + (size_t)nb * 192 + tt * 64 + mt * 16 + lg * 4);
#pragma unroll
      for (int nt = 0; nt < 2; ++nt) {
        f32x4 macc = {b2r[nt], b2r[nt], b2r[nt], b2r[nt]};  // bias in C-init
#pragma unroll
        for (int ks = 0; ks < 4; ++ks)
          macc = __builtin_amdgcn_mfma_f32_16x16x32_f16(af[ks], bf[nt][ks], macc, 0, 0, 0);
        acc[mt][nt][0] += fmaxf(macc[0], 0.f) * ew4.x;
        acc[mt][nt][1] += fmaxf(macc[1], 0.f) * ew4.y;
        acc[mt][nt][2] += fmaxf(macc[2], 0.f) * ew4.z;
        acc[mt][nt][3] += fmaxf(macc[3], 0.f) * ew4.w;
      }
    }
    __syncthreads();  // before restage
  }

  // reduce 64 edge rows -> agg (f16), one 64B contiguous store per wave
  float sv[2];
#pragma unroll
  for (int nt = 0; nt < 2; ++nt) {
    float s = 0.f;
#pragma unroll
    for (int mt = 0; mt < 4; ++mt)
#pragma unroll
      for (int r = 0; r < 4; ++r) s += acc[mt][nt][r];
    s += __shfl_xor(s, 16);
    s += __shfl_xor(s, 32);
    sv[nt] = s;
  }
  if (lane < 32)
    aggh[(size_t)nb * HID_ + nh * 32 + lane] = (_Float16)((lane < 16) ? sv[0] : sv[1]);
}

// ---------------- Kernel 3: output MLP via MFMA, 16 nodes/block (256 blocks) ----------------
// wave w owns cols w*32..+31 for fc1/fc2; waves 0,1 own mu cols w*16..+15.
__global__ void __launch_bounds__(256)
out_mlp(const float* __restrict__ x, const _Float16* __restrict__ xh,
        const _Float16* __restrict__ aggh, const _Float16* __restrict__ fc1f,
        const float* __restrict__ fc1b, const _Float16* __restrict__ fc2f,
        const float* __restrict__ fc2b, const _Float16* __restrict__ muf,
        const float* __restrict__ mub, float* __restrict__ out) {
  const int t = threadIdx.x;
  const int lane = t & 63, l15 = lane & 15, lg = lane >> 4;
  const int w = t >> 6;
  const int nb = blockIdx.x * 16;

  __shared__ __align__(16) _Float16 p1h[16][136];
  __shared__ __align__(16) _Float16 p2h[16][136];

  const int arow = nb + l15;

  // ---- fc1: cols w*32 (nt 0..1), K=160 (5 ks) ----
  float4 acc1[2];
#pragma unroll
  for (int nt = 0; nt < 2; ++nt) {
    const float bias = fc1b[w * 32 + nt * 16 + l15];
    acc1[nt] = {bias, bias, bias, bias};
  }
#pragma unroll
  for (int ks = 0; ks < 5; ++ks) {
    f16x8 af = (ks == 0)
                   ? *(const f16x8*)(xh + (size_t)arow * IN_ + lg * 8)
                   : *(const f16x8*)(aggh + (size_t)arow * HID_ + (ks - 1) * 32 + lg * 8);
#pragma unroll
    for (int nt = 0; nt < 2; ++nt) {
      f16x8 bf = *(const f16x8*)(fc1f + (size_t)((((w * 2 + nt) * 5 + ks) * 64 + lane)) * 8);
      *(f32x4*)&acc1[nt] =
          __builtin_amdgcn_mfma_f32_16x16x32_f16(af, bf, *(f32x4*)&acc1[nt], 0, 0, 0);
    }
  }
#pragma unroll
  for (int nt = 0; nt < 2; ++nt) {
    const int col = w * 32 + nt * 16 + l15;
#pragma unroll
    for (int r = 0; r < 4; ++r)
      p1h[lg * 4 + r][col] = (_Float16)fmaxf(((const float*)&acc1[nt])[r], 0.f);
  }
  __syncthreads();

  // ---- fc2: K=128 (4 ks) ----
  float4 acc2[2];
#pragma unroll
  for (int nt = 0; nt < 2; ++nt) {
    const float bias = fc2b[w * 32 + nt * 16 + l15];
    acc2[nt] = {bias, bias, bias, bias};
  }
#pragma unroll
  for (int ks = 0; ks < 4; ++ks) {
    f16x8 af = *(const f16x8*)&p1h[l15][ks * 32 + lg * 8];
#pragma unroll
    for (int nt = 0; nt < 2; ++nt) {
      f16x8 bf = *(const f16x8*)(fc2f + (size_t)((((w * 2 + nt) * 4 + ks) * 64 + lane)) * 8);
      *(f32x4*)&acc2[nt] =
          __builtin_amdgcn_mfma_f32_16x16x32_f16(af, bf, *(f32x4*)&acc2[nt], 0, 0, 0);
    }
  }
#pragma unroll
  for (int nt = 0; nt < 2; ++nt) {
    const int col = w * 32 + nt * 16 + l15;
#pragma unroll
    for (int r = 0; r < 4; ++r)
      p2h[lg * 4 + r][col] = (_Float16)fmaxf(((const float*)&acc2[nt])[r], 0.f);
  }
  __syncthreads();

  // ---- mu: cols 32 -> waves 0,1; K=128 ----
  if (w < 2) {
    const int col = w * 16 + l15;
    const float mb = mub[col];
    float4 acc3 = {mb, mb, mb, mb};
#pragma unroll
    for (int ks = 0; ks < 4; ++ks) {
      f16x8 af = *(const f16x8*)&p2h[l15][ks * 32 + lg * 8];
      f16x8 bf = *(const f16x8*)(muf + (size_t)(((w * 4 + ks) * 64 + lane)) * 8);
      *(f32x4*)&acc3 = __builtin_amdgcn_mfma_f32_16x16x32_f16(af, bf, *(f32x4*)&acc3, 0, 0, 0);
    }
#pragma unroll
    for (int r = 0; r < 4; ++r) {
      const int node = nb + lg * 4 + r;
      out[(size_t)node * IN_ + col] = x[(size_t)node * IN_ + col] + ((const float*)&acc3)[r];
    }
  }
}

extern "C" void kernel_launch(void* const* d_in, const int* in_sizes, int n_in,
                              void* d_out, int out_size, void* d_ws, size_t ws_size,
                              hipStream_t stream) {
  const float* x     = (const float*)d_in[0];
  const float* edges = (const float*)d_in[1];
  const float* w1    = (const float*)d_in[2];
  const float* b1    = (const float*)d_in[3];
  const float* w2    = (const float*)d_in[4];
  const float* b2    = (const float*)d_in[5];
  const float* fc1w  = (const float*)d_in[6];
  const float* fc1b  = (const float*)d_in[7];
  const float* fc2w  = (const float*)d_in[8];
  const float* fc2b  = (const float*)d_in[9];
  const float* muw   = (const float*)d_in[10];
  const float* mub   = (const float*)d_in[11];
  float* out = (float*)d_out;

  float* ewT    = (float*)d_ws;                         // 4096*192 f32
  _Float16* h1r = (_Float16*)(ewT + (size_t)BV_ * 192); // 3*4096*128
  _Float16* h1s = h1r + (size_t)3 * BV_ * HID_;         // 3*4096*128
  _Float16* w2f = h1s + (size_t)3 * BV_ * HID_;         // 49152
  _Float16* fc1f = w2f + 49152;                         // 20480
  _Float16* fc2f = fc1f + 20480;                        // 16384
  _Float16* muf  = fc2f + 16384;                        // 4096
  _Float16* xh   = muf + 4096;                          // 4096*32
  _Float16* aggh = xh + (size_t)BV_ * IN_;              // 4096*128

  prep_all<<<4832, 256, 0, stream>>>(x, w1, b1, w2, edges, fc1w, fc2w, muw,
                                     h1r, h1s, w2f, fc1f, fc2f, muf, xh, ewT);
  edge_mfma<<<BV_, 256, 0, stream>>>(b2, h1r, h1s, w2f, ewT, aggh);
  out_mlp<<<BV_ / 16, 256, 0, stream>>>(x, xh, aggh, fc1f, fc1b, fc2f, fc2b,
                                        muf, mub, out);
}